// Round 5
// baseline (255.173 us; speedup 1.0000x reference)
//
#include <hip/hip_runtime.h>
#include <cstddef>

#define T_DIM 2048
#define B_DIM 64
#define V_DIM 128
#define LMAX  128
#define ROWF  132                      // floats per em row (129 used; blank at [128])
#define CH    16                       // time steps per staged chunk
#define BUFW  (CH*ROWF)                // 2112 floats = 8448 B per chunk buffer
#define CB    (BUFW*4)                 // 8448 bytes
#define NCH   (T_DIM/CH)               // 128
#define INV_LN2 1.44269504088896340736f
#define LN2F    0.69314718055994530942f
#define NEG2   -1.0e30f

__device__ __forceinline__ float exp2_fast(float x){ return __builtin_amdgcn_exp2f(x); }
__device__ __forceinline__ float log2_fast(float x){ return __builtin_amdgcn_logf(x); }

__device__ __forceinline__ float lae2_log2(float a, float b){
  float m = fmaxf(a, b);
  float d = fabsf(a - b);
  return m + log2_fast(1.0f + exp2_fast(-d));
}
__device__ __forceinline__ float lae3_log2(float a, float b, float c){
  float m = fmaxf(fmaxf(a, b), c);
  return m + log2_fast(exp2_fast(a - m) + exp2_fast(b - m) + exp2_fast(c - m));
}

// DPP wave_shr:1, bound_ctrl=1: lane n <- lane n-1, lane 0 <- 0. Single VALU op.
__device__ __forceinline__ float dpp_shr1_bc(float src){
  return __int_as_float(__builtin_amdgcn_update_dpp(
      0, __float_as_int(src), 0x138, 0xF, 0xF, true));
}
// DPP wave_shr:1 with old: lane 0 keeps `oldv`
__device__ __forceinline__ int dpp_shr1_old(int oldv, int src){
  return __builtin_amdgcn_update_dpp(oldv, src, 0x138, 0xF, 0xF, false);
}

// async global->LDS: 8448 B = 8 x (64 lanes x 16B) + 1 x (64 lanes x 4B)
__device__ __forceinline__ void stage9(const char* gsrc, float* ldst){
  const int lane = threadIdx.x & 63;
  #pragma unroll
  for (int i = 0; i < 8; ++i){
    __builtin_amdgcn_global_load_lds(
      (const __attribute__((address_space(1))) unsigned int*)(gsrc + i*1024 + lane*16),
      (__attribute__((address_space(3))) unsigned int*)((char*)ldst + i*1024),
      16, 0, 0);
  }
  __builtin_amdgcn_global_load_lds(
      (const __attribute__((address_space(1))) unsigned int*)(gsrc + 8192 + lane*4),
      (__attribute__((address_space(3))) unsigned int*)((char*)ldst + 8192),
      4, 0, 0);
}

// ---- Kernel 1: fused softmax + per-b emission-prob stream (linear domain) ----
__global__ __launch_bounds__(256) void em_kernel(const float* __restrict__ acts,
                                                 const int* __restrict__ labels,
                                                 const int* __restrict__ act_lens,
                                                 const int* __restrict__ label_lens,
                                                 float* __restrict__ em){
  const int wid  = threadIdx.x >> 6;
  const int lane = threadIdx.x & 63;
  const int row  = blockIdx.x * 4 + wid;          // row = t*B + b
  const int t = row >> 6;
  const int b = row & (B_DIM - 1);

  __shared__ float sh[4][V_DIM];

  const float2 v = ((const float2*)(acts + (size_t)row * V_DIM))[lane];
  float m = fmaxf(v.x, v.y);
  #pragma unroll
  for (int o = 32; o; o >>= 1) m = fmaxf(m, __shfl_xor(m, o, 64));
  float s = exp2_fast((v.x - m) * INV_LN2) + exp2_fast((v.y - m) * INV_LN2);
  #pragma unroll
  for (int o = 32; o; o >>= 1) s += __shfl_xor(s, o, 64);
  const float d2 = fmaf(m, INV_LN2, log2_fast(s));     // log2 softmax denom

  sh[wid][2 * lane]     = v.x;
  sh[wid][2 * lane + 1] = v.y;

  int masked = (lane < b) ? label_lens[lane] : 0;
  int off = masked;
  #pragma unroll
  for (int o = 1; o < 64; o <<= 1) off += __shfl_xor(off, o, 64);
  const int L = label_lens[b];

  __syncthreads();

  if (t >= act_lens[b]) return;   // rows past act_len are never read downstream

  const int j0 = 2 * lane, j1 = 2 * lane + 1;
  const int lab0 = (j0 < L) ? labels[off + j0] : 0;
  const int lab1 = (j1 < L) ? labels[off + j1] : 0;
  const float p0 = exp2_fast(fmaf(sh[wid][lab0], INV_LN2, -d2));   // linear probs
  const float p1 = exp2_fast(fmaf(sh[wid][lab1], INV_LN2, -d2));

  float* er = em + ((size_t)b * T_DIM + t) * ROWF;
  ((float2*)er)[lane] = make_float2(p0, p1);
  if (lane == 0) er[128] = exp2_fast(fmaf(sh[wid][0], INV_LN2, -d2));  // blank
}

// ---- Kernel 2: TWO per-batch linear-domain CTC recursions per wave ----------
// chain x0 = batch blockIdx.x, chain x1 = batch blockIdx.x+32; instructions
// interleave so one chain's dependency stalls are filled by the other's issue.

#define DECL(S) float S##0,S##1,S##2,S##3,S##4,S##L,S##f0,S##f1,S##s3; int S##K; bool S##sk1;

#define SETUP(S, L_, off_) { \
  const int j0_ = 2*tid, j1_ = 2*tid+1, jm1_ = 2*tid-1; \
  const int lab0_  = (j0_ < (L_)) ? labels[(off_) + j0_] : 0; \
  const int lab1_  = (j1_ < (L_)) ? labels[(off_) + j1_] : 0; \
  const int labm1_ = (tid == 0) ? -1 : ((jm1_ < (L_)) ? labels[(off_) + jm1_] : 0); \
  S##sk1 = (lab0_ != 0) && (lab0_ != labm1_); \
  S##s3  = ((lab1_ != 0) && (lab1_ != lab0_)) ? 1.0f : 0.0f; \
  S##0 = (tid==0)?1.0f:0.0f; S##1=0.0f; S##2=0.0f; S##3=0.0f; S##4=0.0f; \
  S##L = 0.0f; S##f0 = 0.0f; S##f1 = 0.0f; S##K = 0; }

// rescale window boundary (every 8 steps): normalize thread max to [0.5,1)
#define BOUNDARY(S) { \
  float m_ = fmaxf(fmaxf(fmaxf(S##0,S##1),fmaxf(S##2,S##3)),S##4); \
  int e_; (void)frexpf(m_, &e_); \
  const float sc_ = ldexpf(1.0f, -e_); \
  S##0*=sc_; S##1*=sc_; S##2*=sc_; S##3*=sc_; S##4*=sc_; \
  S##K += e_; \
  const int KL_ = dpp_shr1_old(S##K, S##K); \
  if (m_ == 0.0f) S##K = KL_;                    /* dead lane adopts left frame */ \
  int sh_ = KL_ - S##K; \
  if (tid > 0 && sh_ > 40){                      /* own mass negligible vs left */ \
    const int d_ = sh_ - 40; \
    const float dn_ = ldexpf(1.0f, -d_); \
    S##0*=dn_; S##1*=dn_; S##2*=dn_; S##3*=dn_; S##4*=dn_; \
    S##K += d_; sh_ = 40; } \
  const float f_ = ldexpf(1.0f, sh_); \
  S##f0 = (tid == 0) ? 0.0f : f_; \
  S##f1 = S##sk1 ? S##f0 : 0.0f; \
  S##L = dpp_shr1_bc(S##3); }

// one lattice step: 13 VALU ops, n3->dpp produced first (shortest cross-step chain)
#define STEP(S, p0v, p1v, pbv) { \
  const float t3_ = fmaf(S##1, S##s3, S##2) + S##3; \
  const float n3_ = (p1v) * t3_; \
  const float nL_ = dpp_shr1_bc(n3_); \
  const float t0_ = fmaf(S##L, S##f0, S##0); \
  const float t1_ = fmaf(S##L, S##f1, S##0) + S##1; \
  const float n0_ = (pbv) * t0_; \
  const float n1_ = (p0v) * t1_; \
  const float n2_ = (pbv) * (S##2 + S##1); \
  const float n4_ = (pbv) * (S##4 + S##3); \
  S##L = nL_; S##0=n0_; S##1=n1_; S##2=n2_; S##3=n3_; S##4=n4_; }

#define HOIST8(cb, h) \
  float2 P0[8], P1[8]; float PB0[8], PB1[8]; \
  { _Pragma("unroll") \
    for (int k = 0; k < 8; ++k){ \
      const float* r0_ = cb0 + ((h)*8 + k) * ROWF; \
      const float* r1_ = cb1 + ((h)*8 + k) * ROWF; \
      P0[k] = *(const float2*)(r0_ + 2*tid); PB0[k] = r0_[128]; \
      P1[k] = *(const float2*)(r1_ + 2*tid); PB1[k] = r1_[128]; \
    } }

__global__ __launch_bounds__(64) void ctc2_kernel(const float* __restrict__ em,
    const int* __restrict__ labels, const int* __restrict__ act_lens,
    const int* __restrict__ label_lens, float* __restrict__ costs)
{
  __shared__ __align__(16) float sb0[3*BUFW];   // 25.3 KB
  __shared__ __align__(16) float sb1[3*BUFW];   // 25.3 KB
  __shared__ float A0[257], A1[257];
  __shared__ int   KK0[64], KK1[64];

  const int tid = threadIdx.x;
  const int b0 = blockIdx.x;
  const int b1 = blockIdx.x + 32;

  const int L0 = label_lens[b0], L1 = label_lens[b1];
  int alen0 = act_lens[b0]; if (alen0 > T_DIM) alen0 = T_DIM; if (alen0 < 1) alen0 = 1;
  int alen1 = act_lens[b1]; if (alen1 > T_DIM) alen1 = T_DIM; if (alen1 < 1) alen1 = 1;

  // label offsets for both chains (wave butterflies; setup-only cost)
  int off0 = (tid < b0) ? label_lens[tid] : 0;
  int off1 = (tid < b1) ? label_lens[tid] : 0;
  #pragma unroll
  for (int o = 1; o < 64; o <<= 1){
    off0 += __shfl_xor(off0, o, 64);
    off1 += __shfl_xor(off1, o, 64);
  }

  DECL(x0) DECL(x1)
  SETUP(x0, L0, off0)
  SETUP(x1, L1, off1)

  const char* g0 = (const char*)(em + (size_t)b0 * T_DIM * ROWF);
  const char* g1 = (const char*)(em + (size_t)b1 * T_DIM * ROWF);

  stage9(g0,      sb0);          stage9(g1,      sb1);
  stage9(g0 + CB, sb0 + BUFW);   stage9(g1 + CB, sb1 + BUFW);

  const int amax   = (alen0 > alen1) ? alen0 : alen1;
  const int amin   = (alen0 < alen1) ? alen0 : alen1;
  const int ncMax  = (amax + CH - 1) / CH;
  const int ncBoth = amin / CH;

  for (int c = 0; c < ncMax; ++c){
    int cs = c + 2; if (cs > NCH - 1) cs = NCH - 1;     // clamped re-stage at tail
    const int ws = (c + 2) % 3;
    stage9(g0 + (size_t)cs * CB, sb0 + ws * BUFW);
    stage9(g1 + (size_t)cs * CB, sb1 + ws * BUFW);
    asm volatile("s_waitcnt vmcnt(36)" ::: "memory");   // chunk c landed; 2 ahead in flight
    const float* cb0 = sb0 + (c % 3) * BUFW;
    const float* cb1 = sb1 + (c % 3) * BUFW;

    if (c < ncBoth){                                    // both chains fully active
      #pragma unroll
      for (int h = 0; h < 2; ++h){
        HOIST8(cb, h)
        BOUNDARY(x0) BOUNDARY(x1)
        #pragma unroll
        for (int k = 0; k < 8; ++k){
          STEP(x0, P0[k].x, P0[k].y, PB0[k])
          STEP(x1, P1[k].x, P1[k].y, PB1[k])
        }
      }
    } else {                                            // tail: per-step uniform guards
      #pragma unroll
      for (int h = 0; h < 2; ++h){
        HOIST8(cb, h)
        const int tb = c * CH + h * 8;
        if (tb < alen0){ BOUNDARY(x0) }
        if (tb < alen1){ BOUNDARY(x1) }
        #pragma unroll
        for (int k = 0; k < 8; ++k){
          if (tb + k < alen0){ STEP(x0, P0[k].x, P0[k].y, PB0[k]) }
          if (tb + k < alen1){ STEP(x1, P1[k].x, P1[k].y, PB1[k]) }
        }
      }
    }
  }

  A0[4*tid] = x00; A0[4*tid+1] = x01; A0[4*tid+2] = x02; A0[4*tid+3] = x03;
  A1[4*tid] = x10; A1[4*tid+1] = x11; A1[4*tid+2] = x12; A1[4*tid+3] = x13;
  if (tid == 63){ A0[256] = x04; A1[256] = x14; }
  KK0[tid] = x0K; KK1[tid] = x1K;
  __syncthreads();
  if (tid == 0){
    {
      const int sL = 2 * L0;
      int ia = sL >> 2;       if (ia > 63) ia = 63;
      int ib = (sL - 1) >> 2; if (ib > 63) ib = 63;
      const float la = log2_fast(A0[sL])     + (float)KK0[ia];
      const float lb = log2_fast(A0[sL - 1]) + (float)KK0[ib];
      costs[b0] = -LN2F * lae2_log2(la, lb);
    }
    {
      const int sL = 2 * L1;
      int ia = sL >> 2;       if (ia > 63) ia = 63;
      int ib = (sL - 1) >> 2; if (ib > 63) ib = 63;
      const float la = log2_fast(A1[sL])     + (float)KK1[ia];
      const float lb = log2_fast(A1[sL - 1]) + (float)KK1[ib];
      costs[b1] = -LN2F * lae2_log2(la, lb);
    }
  }
}

// ---- Kernel 3: deterministic sum ------------------------------------------
__global__ __launch_bounds__(64) void sum_kernel(const float* __restrict__ costs,
                                                 float* __restrict__ out){
  float v = costs[threadIdx.x];
  #pragma unroll
  for (int o = 32; o; o >>= 1) v += __shfl_xor(v, o, 64);
  if (threadIdx.x == 0) out[0] = v;
}

// ---- Fallback path (proven round-1, if ws too small) -----------------------
__global__ __launch_bounds__(256) void lse_kernel(const float* __restrict__ acts,
                                                  float* __restrict__ denom){
  int row  = (blockIdx.x * 256 + threadIdx.x) >> 6;
  int lane = threadIdx.x & 63;
  if (row >= T_DIM * B_DIM) return;
  const float2 v = ((const float2*)(acts + (size_t)row * V_DIM))[lane];
  float m = fmaxf(v.x, v.y);
  #pragma unroll
  for (int o = 32; o; o >>= 1) m = fmaxf(m, __shfl_xor(m, o, 64));
  float s = exp2_fast((v.x - m) * INV_LN2) + exp2_fast((v.y - m) * INV_LN2);
  #pragma unroll
  for (int o = 32; o; o >>= 1) s += __shfl_xor(s, o, 64);
  if (lane == 0) denom[row] = fmaf(m, INV_LN2, log2_fast(s));
}

__global__ __launch_bounds__(64) void ctc_gather_kernel(
    const float* __restrict__ acts, const int* __restrict__ labels,
    const int* __restrict__ act_lens, const int* __restrict__ label_lens,
    const float* __restrict__ denom, float* __restrict__ costs){
  const int b = blockIdx.x, tid = threadIdx.x;
  const int L = label_lens[b];
  int alen = act_lens[b]; if (alen > T_DIM) alen = T_DIM;
  int masked = (tid < b) ? label_lens[tid] : 0;
  int off = masked;
  #pragma unroll
  for (int o = 1; o < 64; o <<= 1) off += __shfl_xor(off, o, 64);
  const int j0 = 2*tid, j1 = 2*tid+1, jm1 = 2*tid-1;
  const int lab0  = (j0 < L) ? labels[off + j0] : 0;
  const int lab1  = (j1 < L) ? labels[off + j1] : 0;
  const int labm1 = (tid == 0) ? -1 : ((jm1 < L) ? labels[off + jm1] : 0);
  const bool skip1 = (lab0 != 0) && (lab0 != labm1);
  const bool skip3 = (lab1 != 0) && (lab1 != lab0);
  float a0 = (tid == 0) ? 0.0f : NEG2;
  float a1 = NEG2, a2 = NEG2, a3 = NEG2, a4 = NEG2, a3L = NEG2;
  const float* actsB = acts + (size_t)b * V_DIM;
  for (int t = 0; t < alen; ++t){
    const float* base = actsB + (size_t)t * (B_DIM * V_DIM);
    const float d  = denom[t * B_DIM + b];
    const float eb = fmaf(base[0],    INV_LN2, -d);
    const float e0 = fmaf(base[lab0], INV_LN2, -d);
    const float e1 = fmaf(base[lab1], INV_LN2, -d);
    const float c1 = skip1 ? a3L : NEG2;
    const float c3 = skip3 ? a1  : NEG2;
    const float n0 = eb + lae2_log2(a0, a3L);
    const float n1 = e0 + lae3_log2(a1, a0, c1);
    const float n2 = eb + lae2_log2(a2, a1);
    const float n3 = e1 + lae3_log2(a3, a2, c3);
    const float n4 = eb + lae2_log2(a4, a3);
    float nl = __shfl_up(n3, 1, 64);
    a3L = (tid == 0) ? NEG2 : nl;
    a0 = n0; a1 = n1; a2 = n2; a3 = n3; a4 = n4;
  }
  __shared__ float A[257];
  A[4*tid] = a0; A[4*tid+1] = a1; A[4*tid+2] = a2; A[4*tid+3] = a3;
  if (tid == 63) A[256] = a4;
  __syncthreads();
  if (tid == 0){
    const int sL = 2 * L;
    costs[b] = -LN2F * lae2_log2(A[sL], A[sL - 1]);
  }
}

extern "C" void kernel_launch(void* const* d_in, const int* in_sizes, int n_in,
                              void* d_out, int out_size, void* d_ws, size_t ws_size,
                              hipStream_t stream){
  const float* acts       = (const float*)d_in[0];
  const int*   labels     = (const int*)d_in[1];
  const int*   act_lens   = (const int*)d_in[2];
  const int*   label_lens = (const int*)d_in[3];
  float* out = (float*)d_out;

  const size_t em_floats = (size_t)B_DIM * T_DIM * ROWF;
  const size_t need = (em_floats + 64) * sizeof(float);

  if (ws_size >= need){
    float* em    = (float*)d_ws;
    float* costs = em + em_floats;
    em_kernel<<<(T_DIM * B_DIM) / 4, 256, 0, stream>>>(acts, labels, act_lens, label_lens, em);
    ctc2_kernel<<<B_DIM / 2, 64, 0, stream>>>(em, labels, act_lens, label_lens, costs);
    sum_kernel<<<1, 64, 0, stream>>>(costs, out);
  } else {
    float* denom = (float*)d_ws;
    float* costs = denom + (size_t)T_DIM * B_DIM;
    lse_kernel<<<(T_DIM * B_DIM) / 4, 256, 0, stream>>>(acts, denom);
    ctc_gather_kernel<<<B_DIM, 64, 0, stream>>>(acts, labels, act_lens, label_lens, denom, costs);
    sum_kernel<<<1, 64, 0, stream>>>(costs, out);
  }
}

// Round 8
// 151.975 us; speedup vs baseline: 1.6790x; 1.6790x over previous
//
#include <hip/hip_runtime.h>
#include <cstddef>

#define T_DIM 2048
#define B_DIM 64
#define V_DIM 128
#define LMAX  128
#define ROWF  132                      // floats per em row (129 used; blank at [128])
#define INV_LN2 1.44269504088896340736f
#define LN2F    0.69314718055994530942f
#define NEG2   -1.0e30f
#define IMPCAP 1.0e20f

__device__ __forceinline__ float exp2_fast(float x){ return __builtin_amdgcn_exp2f(x); }
__device__ __forceinline__ float log2_fast(float x){ return __builtin_amdgcn_logf(x); }

__device__ __forceinline__ float lae2_log2(float a, float b){
  float m = fmaxf(a, b);
  float d = fabsf(a - b);
  return m + log2_fast(1.0f + exp2_fast(-d));
}
__device__ __forceinline__ float lae3_log2(float a, float b, float c){
  float m = fmaxf(fmaxf(a, b), c);
  return m + log2_fast(exp2_fast(a - m) + exp2_fast(b - m) + exp2_fast(c - m));
}

// DPP wave_shr:1 (validated R3-R5): lane n <- lane n-1.
__device__ __forceinline__ float dpp_shr1_bc(float src){   // lane 0 <- 0
  return __int_as_float(__builtin_amdgcn_update_dpp(
      0, __float_as_int(src), 0x138, 0xF, 0xF, true));
}
__device__ __forceinline__ int dpp_shr1_old_i(int oldv, int src){  // lane 0 keeps oldv
  return __builtin_amdgcn_update_dpp(oldv, src, 0x138, 0xF, 0xF, false);
}

// ---- Kernel 1: fused softmax + per-b emission-prob stream (linear domain) ----
// (unchanged — field-proven R3-R5)
__global__ __launch_bounds__(256) void em_kernel(const float* __restrict__ acts,
                                                 const int* __restrict__ labels,
                                                 const int* __restrict__ act_lens,
                                                 const int* __restrict__ label_lens,
                                                 float* __restrict__ em){
  const int wid  = threadIdx.x >> 6;
  const int lane = threadIdx.x & 63;
  const int row  = blockIdx.x * 4 + wid;          // row = t*B + b
  const int t = row >> 6;
  const int b = row & (B_DIM - 1);

  __shared__ float sh[4][V_DIM];

  const float2 v = ((const float2*)(acts + (size_t)row * V_DIM))[lane];
  float m = fmaxf(v.x, v.y);
  #pragma unroll
  for (int o = 32; o; o >>= 1) m = fmaxf(m, __shfl_xor(m, o, 64));
  float s = exp2_fast((v.x - m) * INV_LN2) + exp2_fast((v.y - m) * INV_LN2);
  #pragma unroll
  for (int o = 32; o; o >>= 1) s += __shfl_xor(s, o, 64);
  const float d2 = fmaf(m, INV_LN2, log2_fast(s));     // log2 softmax denom

  sh[wid][2 * lane]     = v.x;
  sh[wid][2 * lane + 1] = v.y;

  int masked = (lane < b) ? label_lens[lane] : 0;
  int off = masked;
  #pragma unroll
  for (int o = 1; o < 64; o <<= 1) off += __shfl_xor(off, o, 64);
  const int L = label_lens[b];

  __syncthreads();

  if (t >= act_lens[b]) return;   // rows past act_len never read downstream

  const int j0 = 2 * lane, j1 = 2 * lane + 1;
  const int lab0 = (j0 < L) ? labels[off + j0] : 0;
  const int lab1 = (j1 < L) ? labels[off + j1] : 0;
  const float p0 = exp2_fast(fmaf(sh[wid][lab0], INV_LN2, -d2));   // linear probs
  const float p1 = exp2_fast(fmaf(sh[wid][lab1], INV_LN2, -d2));

  float* er = em + ((size_t)b * T_DIM + t) * ROWF;
  ((float2*)er)[lane] = make_float2(p0, p1);
  if (lane == 0) er[128] = exp2_fast(fmaf(sh[wid][0], INV_LN2, -d2));  // blank
}

// ---- Kernel 2: fwd/bwd split; both directions run the identical forward
// recursion (bwd = forward on time-reversed rows + reversed labels; by CTC
// reflection symmetry beta_m(s) = alpha'_{ns'-1}(2L-s)).
// FIX R8a: bwd emission columns are label-reversed (ex0/ex1 == skip-label idx).
// FIX R8b: import capped at 1e20 -> mantissas provably < 2^80, no inf/NaN.

// one lattice step: 14 VALU
#define STEPF(p0v,p1v,pbv) { \
  const float t3_ = fmaf(a1, s3f, a2) + a3; \
  const float n3_ = (p1v) * t3_; \
  const float nL_ = dpp_shr1_bc(n3_); \
  const float imp_ = fminf(aL * f0, IMPCAP); \
  const float t1_ = fmaf(imp_, sk1f, a0) + a1; \
  const float n0_ = (pbv) * (a0 + imp_); \
  const float n1_ = (p0v) * t1_; \
  const float n2_ = (pbv) * (a2 + a1); \
  const float n4_ = (pbv) * (a4 + a3); \
  aL = nL_; a0=n0_; a1=n1_; a2=n2_; a3=n3_; a4=n4_; }

// rescale boundary every 8 steps
#define BOUNDF { \
  float m_ = fmaxf(fmaxf(fmaxf(a0,a1),fmaxf(a2,a3)),a4); \
  int e_; (void)frexpf(m_, &e_); \
  const float sc_ = ldexpf(1.0f, -e_); \
  a0*=sc_; a1*=sc_; a2*=sc_; a3*=sc_; a4*=sc_; \
  K += e_; \
  const int KL_ = dpp_shr1_old_i(K, K); \
  if (m_ == 0.0f) K = KL_; \
  int sh_ = KL_ - K; \
  if (tid > 0 && sh_ > 40){ \
    const int d_ = sh_ - 40; \
    const float dn_ = ldexpf(1.0f, -d_); \
    a0*=dn_; a1*=dn_; a2*=dn_; a3*=dn_; a4*=dn_; \
    K += d_; sh_ = 40; } \
  const float f_ = ldexpf(1.0f, sh_); \
  f0 = (tid == 0) ? 0.0f : f_; \
  aL = dpp_shr1_bc(a3); }

// load 8 rows (row = rbase + rsgn*i, i clamped to [0, ns1]); per-lane fixed
// emission columns ex0/ex1 (direction-dependent), blank at col 128
#define LOADD(BUF, BBUF, bi0) { _Pragma("unroll") \
  for (int k_ = 0; k_ < 8; ++k_){ \
    int i_ = (bi0) + k_; if (i_ > ns1) i_ = ns1; \
    const float* r_ = em_b + (size_t)(rbase + rsgn * i_) * ROWF; \
    BUF[k_].x = r_[ex0]; BUF[k_].y = r_[ex1]; BBUF[k_] = r_[128]; } }

__global__ __launch_bounds__(512) void ctcfb_kernel(const float* __restrict__ em,
    const int* __restrict__ labels, const int* __restrict__ act_lens,
    const int* __restrict__ label_lens, float* __restrict__ costs)
{
  __shared__ float Bsh[4][260];
  __shared__ int   Ksh[4][64];

  const int tid = threadIdx.x & 63;
  const int w   = threadIdx.x >> 6;
  const int bi  = w >> 1;
  const int dir = w & 1;
  const int b   = blockIdx.x * 4 + bi;

  const int L = label_lens[b];
  int alen = act_lens[b]; if (alen > T_DIM) alen = T_DIM; if (alen < 1) alen = 1;
  const int m = alen >> 1;

  int off = (tid < b) ? label_lens[tid] : 0;
  #pragma unroll
  for (int o = 1; o < 64; o <<= 1) off += __shfl_xor(off, o, 64);

  // direction-dependent label indices: fwd l[j], bwd rl[j] = l[L-1-j]
  const int j0 = 2*tid, j1 = 2*tid + 1, jm = 2*tid - 1;
  const int i0 = dir ? (L - 1 - j0) : j0;
  const int i1 = dir ? (L - 1 - j1) : j1;
  const int im = dir ? (L - 1 - jm) : jm;
  const int lab0  = (j0 < L) ? labels[off + i0] : 0;
  const int lab1  = (j1 < L) ? labels[off + i1] : 0;
  const int labm1 = (tid == 0) ? -1 : ((jm < L) ? labels[off + im] : 0);
  const bool  sk1 = (lab0 != 0) && (lab0 != labm1);
  const float sk1f = sk1 ? 1.0f : 0.0f;
  const float s3f = ((lab1 != 0) && (lab1 != lab0)) ? 1.0f : 0.0f;

  // emission columns match the label indices above (clamped; clamped lanes
  // are garbage lattice states that never feed back)
  const int ex0 = (i0 < 0) ? 0 : i0;
  const int ex1 = (i1 < 0) ? 0 : i1;

  const int ns  = dir ? (alen - m) : m;        // steps this wave runs
  int ns1 = ns - 1; if (ns1 < 0) ns1 = 0;
  const int rbase = dir ? (alen - 1) : 0;      // row = rbase + rsgn*i
  const int rsgn  = dir ? -1 : 1;
  const float* em_b = em + (size_t)b * T_DIM * ROWF;

  float a0 = (tid == 0) ? 1.0f : 0.0f;
  float a1 = 0.f, a2 = 0.f, a3 = 0.f, a4 = 0.f;
  float aL = 0.f, f0 = 0.f;
  int K = 0;

  float2 P[8], Q[8]; float Pb[8], Qb[8];
  if (ns > 0){ LOADD(P, Pb, 0) }
  int done = 0;
  for (; done + 16 <= ns; done += 16){
    LOADD(Q, Qb, done + 8)
    BOUNDF
    #pragma unroll
    for (int k = 0; k < 8; ++k) STEPF(P[k].x, P[k].y, Pb[k])
    LOADD(P, Pb, done + 16)
    BOUNDF
    #pragma unroll
    for (int k = 0; k < 8; ++k) STEPF(Q[k].x, Q[k].y, Qb[k])
  }
  const int remv = ns - done;
  if (remv >= 8){
    LOADD(Q, Qb, done + 8)
    BOUNDF
    #pragma unroll
    for (int k = 0; k < 8; ++k) STEPF(P[k].x, P[k].y, Pb[k])
    const int r2 = remv - 8;
    if (r2 > 0){
      BOUNDF
      #pragma unroll
      for (int k = 0; k < 8; ++k){ if (k < r2) STEPF(Q[k].x, Q[k].y, Qb[k]) }
    }
  } else if (remv > 0){
    BOUNDF
    #pragma unroll
    for (int k = 0; k < 8; ++k){ if (k < remv) STEPF(P[k].x, P[k].y, Pb[k]) }
  }

  if (dir){
    // publish beta-side alpha' (reversed-state mantissas) + per-lane exponent
    Bsh[bi][4*tid]   = a0; Bsh[bi][4*tid+1] = a1;
    Bsh[bi][4*tid+2] = a2; Bsh[bi][4*tid+3] = a3;
    if (tid == 63) Bsh[bi][256] = a4;
    Ksh[bi][tid] = K;
  }
  __syncthreads();

  if (!dir){
    // alphabar: emission-free predecessor-sum of alpha_{m-1}
    const float impE = fminf(aL * f0, IMPCAP);
    const float al0 = a0 + impE;
    const float al1 = fmaf(impE, sk1f, a0) + a1;
    const float al2 = a2 + a1;
    const float al3 = fmaf(a1, s3f, a2) + a3;
    const float al4 = a4 + a3;                   // state 256 (lane 63)
    const float alq[4] = {al0, al1, al2, al3};

    const float* Bb  = Bsh[bi];
    const int*   Kbp = Ksh[bi];
    const int twoL = 2 * L;

    // P = sum_s alphabar(s) * beta_m(s),  beta_m(s) = alpha'(2L - s)
    // logs taken separately (product could overflow f32 in capped regimes)
    float v = NEG2;
    #pragma unroll
    for (int q = 0; q < 4; ++q){
      const int s = 4*tid + q;
      const int u = twoL - s;
      if (u >= 0){
        int ul = u >> 2; if (ul > 63) ul = 63;
        const float av = alq[q], bv = Bb[u];
        if (av > 0.0f && bv > 0.0f)
          v = lae2_log2(v, log2_fast(av) + log2_fast(bv) + (float)(K + Kbp[ul]));
      }
    }
    if (tid == 63){
      const int u = twoL - 256;                  // only L=128 hits this
      if (u >= 0 && al4 > 0.0f && Bb[u] > 0.0f)
        v = lae2_log2(v, log2_fast(al4) + log2_fast(Bb[u]) + (float)(K + Kbp[u >> 2]));
    }
    #pragma unroll
    for (int o = 1; o < 64; o <<= 1){
      const float u2 = __shfl_xor(v, o, 64);
      v = lae2_log2(v, u2);
    }
    if (tid == 0) costs[b] = -LN2F * v;
  }
}

// ---- Kernel 3: deterministic sum ------------------------------------------
__global__ __launch_bounds__(64) void sum_kernel(const float* __restrict__ costs,
                                                 float* __restrict__ out){
  float v = costs[threadIdx.x];
  #pragma unroll
  for (int o = 32; o; o >>= 1) v += __shfl_xor(v, o, 64);
  if (threadIdx.x == 0) out[0] = v;
}

// ---- Fallback path (proven round-1, if ws too small) -----------------------
__global__ __launch_bounds__(256) void lse_kernel(const float* __restrict__ acts,
                                                  float* __restrict__ denom){
  int row  = (blockIdx.x * 256 + threadIdx.x) >> 6;
  int lane = threadIdx.x & 63;
  if (row >= T_DIM * B_DIM) return;
  const float2 v = ((const float2*)(acts + (size_t)row * V_DIM))[lane];
  float m = fmaxf(v.x, v.y);
  #pragma unroll
  for (int o = 32; o; o >>= 1) m = fmaxf(m, __shfl_xor(m, o, 64));
  float s = exp2_fast((v.x - m) * INV_LN2) + exp2_fast((v.y - m) * INV_LN2);
  #pragma unroll
  for (int o = 32; o; o >>= 1) s += __shfl_xor(s, o, 64);
  if (lane == 0) denom[row] = fmaf(m, INV_LN2, log2_fast(s));
}

__global__ __launch_bounds__(64) void ctc_gather_kernel(
    const float* __restrict__ acts, const int* __restrict__ labels,
    const int* __restrict__ act_lens, const int* __restrict__ label_lens,
    const float* __restrict__ denom, float* __restrict__ costs){
  const int b = blockIdx.x, tid = threadIdx.x;
  const int L = label_lens[b];
  int alen = act_lens[b]; if (alen > T_DIM) alen = T_DIM;
  int masked = (tid < b) ? label_lens[tid] : 0;
  int off = masked;
  #pragma unroll
  for (int o = 1; o < 64; o <<= 1) off += __shfl_xor(off, o, 64);
  const int j0 = 2*tid, j1 = 2*tid+1, jm1 = 2*tid-1;
  const int lab0  = (j0 < L) ? labels[off + j0] : 0;
  const int lab1  = (j1 < L) ? labels[off + j1] : 0;
  const int labm1 = (tid == 0) ? -1 : ((jm1 < L) ? labels[off + jm1] : 0);
  const bool skip1 = (lab0 != 0) && (lab0 != labm1);
  const bool skip3 = (lab1 != 0) && (lab1 != lab0);
  float a0 = (tid == 0) ? 0.0f : NEG2;
  float a1 = NEG2, a2 = NEG2, a3 = NEG2, a4 = NEG2, a3L = NEG2;
  const float* actsB = acts + (size_t)b * V_DIM;
  for (int t = 0; t < alen; ++t){
    const float* base = actsB + (size_t)t * (B_DIM * V_DIM);
    const float d  = denom[t * B_DIM + b];
    const float eb = fmaf(base[0],    INV_LN2, -d);
    const float e0 = fmaf(base[lab0], INV_LN2, -d);
    const float e1 = fmaf(base[lab1], INV_LN2, -d);
    const float c1 = skip1 ? a3L : NEG2;
    const float c3 = skip3 ? a1  : NEG2;
    const float n0 = eb + lae2_log2(a0, a3L);
    const float n1 = e0 + lae3_log2(a1, a0, c1);
    const float n2 = eb + lae2_log2(a2, a1);
    const float n3 = e1 + lae3_log2(a3, a2, c3);
    const float n4 = eb + lae2_log2(a4, a3);
    float nl = __shfl_up(n3, 1, 64);
    a3L = (tid == 0) ? NEG2 : nl;
    a0 = n0; a1 = n1; a2 = n2; a3 = n3; a4 = n4;
  }
  __shared__ float A[257];
  A[4*tid] = a0; A[4*tid+1] = a1; A[4*tid+2] = a2; A[4*tid+3] = a3;
  if (tid == 63) A[256] = a4;
  __syncthreads();
  if (tid == 0){
    const int sL = 2 * L;
    costs[b] = -LN2F * lae2_log2(A[sL], A[sL - 1]);
  }
}

extern "C" void kernel_launch(void* const* d_in, const int* in_sizes, int n_in,
                              void* d_out, int out_size, void* d_ws, size_t ws_size,
                              hipStream_t stream){
  const float* acts       = (const float*)d_in[0];
  const int*   labels     = (const int*)d_in[1];
  const int*   act_lens   = (const int*)d_in[2];
  const int*   label_lens = (const int*)d_in[3];
  float* out = (float*)d_out;

  const size_t em_floats = (size_t)B_DIM * T_DIM * ROWF;
  const size_t need = (em_floats + 64) * sizeof(float);

  if (ws_size >= need){
    float* em    = (float*)d_ws;
    float* costs = em + em_floats;
    em_kernel<<<(T_DIM * B_DIM) / 4, 256, 0, stream>>>(acts, labels, act_lens, label_lens, em);
    ctcfb_kernel<<<B_DIM / 4, 512, 0, stream>>>(em, labels, act_lens, label_lens, costs);
    sum_kernel<<<1, 64, 0, stream>>>(costs, out);
  } else {
    float* denom = (float*)d_ws;
    float* costs = denom + (size_t)T_DIM * B_DIM;
    lse_kernel<<<(T_DIM * B_DIM) / 4, 256, 0, stream>>>(acts, denom);
    ctc_gather_kernel<<<B_DIM, 64, 0, stream>>>(acts, labels, act_lens, label_lens, denom, costs);
    sum_kernel<<<1, 64, 0, stream>>>(costs, out);
  }
}

// Round 9
// 116.784 us; speedup vs baseline: 2.1850x; 1.3013x over previous
//
#include <hip/hip_runtime.h>
#include <cstddef>

#define T_DIM 2048
#define B_DIM 64
#define V_DIM 128
#define LMAX  128
#define ROWF  132                      // floats per em row (129 used; blank at [128])
#define EMF   ((size_t)B_DIM * T_DIM * ROWF)
#define INV_LN2 1.44269504088896340736f
#define LN2F    0.69314718055994530942f
#define NEG2   -1.0e30f
#define IMPCAP 1.0e20f

__device__ __forceinline__ float exp2_fast(float x){ return __builtin_amdgcn_exp2f(x); }
__device__ __forceinline__ float log2_fast(float x){ return __builtin_amdgcn_logf(x); }

__device__ __forceinline__ float lae2_log2(float a, float b){
  float m = fmaxf(a, b);
  float d = fabsf(a - b);
  return m + log2_fast(1.0f + exp2_fast(-d));
}
__device__ __forceinline__ float lae3_log2(float a, float b, float c){
  float m = fmaxf(fmaxf(a, b), c);
  return m + log2_fast(exp2_fast(a - m) + exp2_fast(b - m) + exp2_fast(c - m));
}

// DPP wave_shr:1 (validated R3-R8): lane n <- lane n-1.
__device__ __forceinline__ float dpp_shr1_bc(float src){   // lane 0 <- 0
  return __int_as_float(__builtin_amdgcn_update_dpp(
      0, __float_as_int(src), 0x138, 0xF, 0xF, true));
}
__device__ __forceinline__ int dpp_shr1_old_i(int oldv, int src){  // lane 0 keeps oldv
  return __builtin_amdgcn_update_dpp(oldv, src, 0x138, 0xF, 0xF, false);
}

// ---- shared step/boundary macros (R8-proven algebra) -----------------------
#define STEPF(p0v,p1v,pbv) { \
  const float t3_ = fmaf(a1, s3f, a2) + a3; \
  const float n3_ = (p1v) * t3_; \
  const float nL_ = dpp_shr1_bc(n3_); \
  const float imp_ = fminf(aL * f0, IMPCAP); \
  const float t1_ = fmaf(imp_, sk1f, a0) + a1; \
  const float n0_ = (pbv) * (a0 + imp_); \
  const float n1_ = (p0v) * t1_; \
  const float n2_ = (pbv) * (a2 + a1); \
  const float n4_ = (pbv) * (a4 + a3); \
  aL = nL_; a0=n0_; a1=n1_; a2=n2_; a3=n3_; a4=n4_; }

#define BOUNDF { \
  float m_ = fmaxf(fmaxf(fmaxf(a0,a1),fmaxf(a2,a3)),a4); \
  int e_; (void)frexpf(m_, &e_); \
  const float sc_ = ldexpf(1.0f, -e_); \
  a0*=sc_; a1*=sc_; a2*=sc_; a3*=sc_; a4*=sc_; \
  K += e_; \
  const int KL_ = dpp_shr1_old_i(K, K); \
  if (m_ == 0.0f) K = KL_; \
  int sh_ = KL_ - K; \
  if (tid > 0 && sh_ > 40){ \
    const int d_ = sh_ - 40; \
    const float dn_ = ldexpf(1.0f, -d_); \
    a0*=dn_; a1*=dn_; a2*=dn_; a3*=dn_; a4*=dn_; \
    K += d_; sh_ = 40; } \
  const float f_ = ldexpf(1.0f, sh_); \
  f0 = (tid == 0) ? 0.0f : f_; \
  aL = dpp_shr1_bc(a3); }

// ---- Kernel 1 (primary): fused softmax + DUAL emission streams -------------
// em_f[b][t][2l..] = p(l[2l]), p(l[2l+1]);  em_r[b][t][2l..] = p(l[L-1-2l]),
// p(l[L-2-2l]) (label-reversed layout for the bwd wave); blank at [128] both.
__global__ __launch_bounds__(256) void em2_kernel(const float* __restrict__ acts,
                                                  const int* __restrict__ labels,
                                                  const int* __restrict__ act_lens,
                                                  const int* __restrict__ label_lens,
                                                  float* __restrict__ em_f,
                                                  float* __restrict__ em_r){
  const int wid  = threadIdx.x >> 6;
  const int lane = threadIdx.x & 63;
  const int row  = blockIdx.x * 4 + wid;          // row = t*B + b
  const int t = row >> 6;
  const int b = row & (B_DIM - 1);

  __shared__ float sh[4][V_DIM];

  const float2 v = ((const float2*)(acts + (size_t)row * V_DIM))[lane];
  float m = fmaxf(v.x, v.y);
  #pragma unroll
  for (int o = 32; o; o >>= 1) m = fmaxf(m, __shfl_xor(m, o, 64));
  float s = exp2_fast((v.x - m) * INV_LN2) + exp2_fast((v.y - m) * INV_LN2);
  #pragma unroll
  for (int o = 32; o; o >>= 1) s += __shfl_xor(s, o, 64);
  const float d2 = fmaf(m, INV_LN2, log2_fast(s));     // log2 softmax denom

  sh[wid][2 * lane]     = v.x;
  sh[wid][2 * lane + 1] = v.y;

  int masked = (lane < b) ? label_lens[lane] : 0;
  int off = masked;
  #pragma unroll
  for (int o = 1; o < 64; o <<= 1) off += __shfl_xor(off, o, 64);
  const int L = label_lens[b];

  __syncthreads();

  if (t >= act_lens[b]) return;   // rows past act_len never read downstream

  const int j0 = 2 * lane, j1 = 2 * lane + 1;
  const int lab0 = (j0 < L) ? labels[off + j0] : 0;
  const int lab1 = (j1 < L) ? labels[off + j1] : 0;
  const int lr0  = (j0 < L) ? labels[off + (L - 1 - j0)] : 0;
  const int lr1  = (j1 < L) ? labels[off + (L - 1 - j1)] : 0;

  const float p0  = exp2_fast(fmaf(sh[wid][lab0], INV_LN2, -d2));
  const float p1  = exp2_fast(fmaf(sh[wid][lab1], INV_LN2, -d2));
  const float pr0 = exp2_fast(fmaf(sh[wid][lr0],  INV_LN2, -d2));
  const float pr1 = exp2_fast(fmaf(sh[wid][lr1],  INV_LN2, -d2));
  const float pb  = exp2_fast(fmaf(sh[wid][0],    INV_LN2, -d2));

  float* ef = em_f + ((size_t)b * T_DIM + t) * ROWF;
  float* er = em_r + ((size_t)b * T_DIM + t) * ROWF;
  ((float2*)ef)[lane] = make_float2(p0, p1);
  ((float2*)er)[lane] = make_float2(pr0, pr1);
  if (lane == 0){ ef[128] = pb; er[128] = pb; }
}

// ---- Kernel 2 (primary): one wave per (b,dir), 128 blocks x 64 threads -----
// Both directions run the identical forward recursion (bwd reads em_r with
// time reversed). Results published to ws; combine done by comb_kernel.
#define LOAD2D(BUF, BBUF, bi0) { _Pragma("unroll") \
  for (int k_ = 0; k_ < 8; ++k_){ \
    int i_ = (bi0) + k_; if (i_ > ns1) i_ = ns1; \
    const float* r_ = em_b + (size_t)(rbase + rsgn * i_) * ROWF; \
    BUF[k_] = *(const float2*)(r_ + 2*tid); BBUF[k_] = r_[128]; } }

__global__ __launch_bounds__(64) void ctcfb2_kernel(const float* __restrict__ em_f,
    const float* __restrict__ em_r, const int* __restrict__ labels,
    const int* __restrict__ act_lens, const int* __restrict__ label_lens,
    float* __restrict__ AL, int* __restrict__ KF,
    float* __restrict__ BB, int* __restrict__ KB)
{
  const int tid = threadIdx.x;
  const int b   = blockIdx.x >> 1;
  const int dir = blockIdx.x & 1;

  const int L = label_lens[b];
  int alen = act_lens[b]; if (alen > T_DIM) alen = T_DIM; if (alen < 1) alen = 1;
  const int m = alen >> 1;

  int off = (tid < b) ? label_lens[tid] : 0;
  #pragma unroll
  for (int o = 1; o < 64; o <<= 1) off += __shfl_xor(off, o, 64);

  // skip flags from direction-dependent labels (emissions coherent by layout)
  const int j0 = 2*tid, j1 = 2*tid + 1, jm = 2*tid - 1;
  const int i0 = dir ? (L - 1 - j0) : j0;
  const int i1 = dir ? (L - 1 - j1) : j1;
  const int im = dir ? (L - 1 - jm) : jm;
  const int lab0  = (j0 < L) ? labels[off + i0] : 0;
  const int lab1  = (j1 < L) ? labels[off + i1] : 0;
  const int labm1 = (tid == 0) ? -1 : ((jm < L) ? labels[off + im] : 0);
  const float sk1f = ((lab0 != 0) && (lab0 != labm1)) ? 1.0f : 0.0f;
  const float s3f  = ((lab1 != 0) && (lab1 != lab0)) ? 1.0f : 0.0f;

  const int ns  = dir ? (alen - m) : m;
  int ns1 = ns - 1; if (ns1 < 0) ns1 = 0;
  const int rbase = dir ? (alen - 1) : 0;
  const int rsgn  = dir ? -1 : 1;
  const float* em_b = (dir ? em_r : em_f) + (size_t)b * T_DIM * ROWF;

  float a0 = (tid == 0) ? 1.0f : 0.0f;
  float a1 = 0.f, a2 = 0.f, a3 = 0.f, a4 = 0.f;
  float aL = 0.f, f0 = 0.f;
  int K = 0;

  float2 P[8], Q[8], R[8]; float Pb[8], Qb[8], Rb[8];
  LOAD2D(P, Pb, 0) LOAD2D(Q, Qb, 8) LOAD2D(R, Rb, 16)   // 48 loads in flight

  int done = 0;
  for (; done + 24 <= ns; done += 24){
    BOUNDF
    #pragma unroll
    for (int k = 0; k < 8; ++k) STEPF(P[k].x, P[k].y, Pb[k])
    LOAD2D(P, Pb, done + 24)
    BOUNDF
    #pragma unroll
    for (int k = 0; k < 8; ++k) STEPF(Q[k].x, Q[k].y, Qb[k])
    LOAD2D(Q, Qb, done + 32)
    BOUNDF
    #pragma unroll
    for (int k = 0; k < 8; ++k) STEPF(R[k].x, R[k].y, Rb[k])
    LOAD2D(R, Rb, done + 40)
  }
  const int r = ns - done;                 // 0..23; buffers hold rows done..done+24
  if (r > 0){
    BOUNDF
    #pragma unroll
    for (int k = 0; k < 8; ++k){ if (k < r) STEPF(P[k].x, P[k].y, Pb[k]) }
  }
  if (r > 8){
    BOUNDF
    #pragma unroll
    for (int k = 0; k < 8; ++k){ if (8 + k < r) STEPF(Q[k].x, Q[k].y, Qb[k]) }
  }
  if (r > 16){
    BOUNDF
    #pragma unroll
    for (int k = 0; k < 8; ++k){ if (16 + k < r) STEPF(R[k].x, R[k].y, Rb[k]) }
  }

  if (dir){
    BB[b*260 + 4*tid]     = a0; BB[b*260 + 4*tid + 1] = a1;
    BB[b*260 + 4*tid + 2] = a2; BB[b*260 + 4*tid + 3] = a3;
    if (tid == 63) BB[b*260 + 256] = a4;
    KB[b*64 + tid] = K;
  } else {
    const float impE = fminf(aL * f0, IMPCAP);
    AL[b*260 + 4*tid]     = a0 + impE;
    AL[b*260 + 4*tid + 1] = fmaf(impE, sk1f, a0) + a1;
    AL[b*260 + 4*tid + 2] = a2 + a1;
    AL[b*260 + 4*tid + 3] = fmaf(a1, s3f, a2) + a3;
    if (tid == 63) AL[b*260 + 256] = a4 + a3;
    KF[b*64 + tid] = K;
  }
}

// ---- Kernel 3 (primary): per-b combine P = sum_s alphabar(s)*beta_m(s) ----
__global__ __launch_bounds__(64) void comb_kernel(const float* __restrict__ AL,
    const int* __restrict__ KF, const float* __restrict__ BB,
    const int* __restrict__ KB, const int* __restrict__ label_lens,
    float* __restrict__ costs)
{
  const int b = blockIdx.x, tid = threadIdx.x;
  const int twoL = 2 * label_lens[b];
  const int Kf = KF[b*64 + tid];

  float v = NEG2;
  #pragma unroll
  for (int q = 0; q < 4; ++q){
    const int s = 4*tid + q;
    const int u = twoL - s;
    if (u >= 0){
      int ul = u >> 2; if (ul > 63) ul = 63;
      const float av = AL[b*260 + s], bv = BB[b*260 + u];
      if (av > 0.0f && bv > 0.0f)
        v = lae2_log2(v, log2_fast(av) + log2_fast(bv)
                         + (float)(Kf + KB[b*64 + ul]));
    }
  }
  if (tid == 63){
    const int u = twoL - 256;               // only L=128 hits this
    const float av = AL[b*260 + 256];
    if (u >= 0 && av > 0.0f && BB[b*260 + u] > 0.0f)
      v = lae2_log2(v, log2_fast(av) + log2_fast(BB[b*260 + u])
                       + (float)(Kf + KB[b*64 + (u >> 2)]));
  }
  #pragma unroll
  for (int o = 1; o < 64; o <<= 1){
    const float u2 = __shfl_xor(v, o, 64);
    v = lae2_log2(v, u2);
  }
  if (tid == 0) costs[b] = -LN2F * v;
}

// ---- Kernel 4: deterministic sum ------------------------------------------
__global__ __launch_bounds__(64) void sum_kernel(const float* __restrict__ costs,
                                                 float* __restrict__ out){
  float v = costs[threadIdx.x];
  #pragma unroll
  for (int o = 32; o; o >>= 1) v += __shfl_xor(v, o, 64);
  if (threadIdx.x == 0) out[0] = v;
}

// ============== R8 PROVEN PATH (fallback when ws < dual-em size) =============
__global__ __launch_bounds__(256) void em_kernel(const float* __restrict__ acts,
                                                 const int* __restrict__ labels,
                                                 const int* __restrict__ act_lens,
                                                 const int* __restrict__ label_lens,
                                                 float* __restrict__ em){
  const int wid  = threadIdx.x >> 6;
  const int lane = threadIdx.x & 63;
  const int row  = blockIdx.x * 4 + wid;
  const int t = row >> 6;
  const int b = row & (B_DIM - 1);
  __shared__ float sh[4][V_DIM];
  const float2 v = ((const float2*)(acts + (size_t)row * V_DIM))[lane];
  float m = fmaxf(v.x, v.y);
  #pragma unroll
  for (int o = 32; o; o >>= 1) m = fmaxf(m, __shfl_xor(m, o, 64));
  float s = exp2_fast((v.x - m) * INV_LN2) + exp2_fast((v.y - m) * INV_LN2);
  #pragma unroll
  for (int o = 32; o; o >>= 1) s += __shfl_xor(s, o, 64);
  const float d2 = fmaf(m, INV_LN2, log2_fast(s));
  sh[wid][2 * lane]     = v.x;
  sh[wid][2 * lane + 1] = v.y;
  int masked = (lane < b) ? label_lens[lane] : 0;
  int off = masked;
  #pragma unroll
  for (int o = 1; o < 64; o <<= 1) off += __shfl_xor(off, o, 64);
  const int L = label_lens[b];
  __syncthreads();
  if (t >= act_lens[b]) return;
  const int j0 = 2 * lane, j1 = 2 * lane + 1;
  const int lab0 = (j0 < L) ? labels[off + j0] : 0;
  const int lab1 = (j1 < L) ? labels[off + j1] : 0;
  const float p0 = exp2_fast(fmaf(sh[wid][lab0], INV_LN2, -d2));
  const float p1 = exp2_fast(fmaf(sh[wid][lab1], INV_LN2, -d2));
  float* er = em + ((size_t)b * T_DIM + t) * ROWF;
  ((float2*)er)[lane] = make_float2(p0, p1);
  if (lane == 0) er[128] = exp2_fast(fmaf(sh[wid][0], INV_LN2, -d2));
}

#define LOADD(BUF, BBUF, bi0) { _Pragma("unroll") \
  for (int k_ = 0; k_ < 8; ++k_){ \
    int i_ = (bi0) + k_; if (i_ > ns1) i_ = ns1; \
    const float* r_ = em_b + (size_t)(rbase + rsgn * i_) * ROWF; \
    BUF[k_].x = r_[ex0]; BUF[k_].y = r_[ex1]; BBUF[k_] = r_[128]; } }

__global__ __launch_bounds__(512) void ctcfb_kernel(const float* __restrict__ em,
    const int* __restrict__ labels, const int* __restrict__ act_lens,
    const int* __restrict__ label_lens, float* __restrict__ costs)
{
  __shared__ float Bsh[4][260];
  __shared__ int   Ksh[4][64];
  const int tid = threadIdx.x & 63;
  const int w   = threadIdx.x >> 6;
  const int bi  = w >> 1;
  const int dir = w & 1;
  const int b   = blockIdx.x * 4 + bi;
  const int L = label_lens[b];
  int alen = act_lens[b]; if (alen > T_DIM) alen = T_DIM; if (alen < 1) alen = 1;
  const int m = alen >> 1;
  int off = (tid < b) ? label_lens[tid] : 0;
  #pragma unroll
  for (int o = 1; o < 64; o <<= 1) off += __shfl_xor(off, o, 64);
  const int j0 = 2*tid, j1 = 2*tid + 1, jm = 2*tid - 1;
  const int i0 = dir ? (L - 1 - j0) : j0;
  const int i1 = dir ? (L - 1 - j1) : j1;
  const int im = dir ? (L - 1 - jm) : jm;
  const int lab0  = (j0 < L) ? labels[off + i0] : 0;
  const int lab1  = (j1 < L) ? labels[off + i1] : 0;
  const int labm1 = (tid == 0) ? -1 : ((jm < L) ? labels[off + im] : 0);
  const float sk1f = ((lab0 != 0) && (lab0 != labm1)) ? 1.0f : 0.0f;
  const float s3f = ((lab1 != 0) && (lab1 != lab0)) ? 1.0f : 0.0f;
  const int ex0 = (i0 < 0) ? 0 : i0;
  const int ex1 = (i1 < 0) ? 0 : i1;
  const int ns  = dir ? (alen - m) : m;
  int ns1 = ns - 1; if (ns1 < 0) ns1 = 0;
  const int rbase = dir ? (alen - 1) : 0;
  const int rsgn  = dir ? -1 : 1;
  const float* em_b = em + (size_t)b * T_DIM * ROWF;
  float a0 = (tid == 0) ? 1.0f : 0.0f;
  float a1 = 0.f, a2 = 0.f, a3 = 0.f, a4 = 0.f;
  float aL = 0.f, f0 = 0.f;
  int K = 0;
  float2 P[8], Q[8]; float Pb[8], Qb[8];
  if (ns > 0){ LOADD(P, Pb, 0) }
  int done = 0;
  for (; done + 16 <= ns; done += 16){
    LOADD(Q, Qb, done + 8)
    BOUNDF
    #pragma unroll
    for (int k = 0; k < 8; ++k) STEPF(P[k].x, P[k].y, Pb[k])
    LOADD(P, Pb, done + 16)
    BOUNDF
    #pragma unroll
    for (int k = 0; k < 8; ++k) STEPF(Q[k].x, Q[k].y, Qb[k])
  }
  const int remv = ns - done;
  if (remv >= 8){
    LOADD(Q, Qb, done + 8)
    BOUNDF
    #pragma unroll
    for (int k = 0; k < 8; ++k) STEPF(P[k].x, P[k].y, Pb[k])
    const int r2 = remv - 8;
    if (r2 > 0){
      BOUNDF
      #pragma unroll
      for (int k = 0; k < 8; ++k){ if (k < r2) STEPF(Q[k].x, Q[k].y, Qb[k]) }
    }
  } else if (remv > 0){
    BOUNDF
    #pragma unroll
    for (int k = 0; k < 8; ++k){ if (k < remv) STEPF(P[k].x, P[k].y, Pb[k]) }
  }
  if (dir){
    Bsh[bi][4*tid]   = a0; Bsh[bi][4*tid+1] = a1;
    Bsh[bi][4*tid+2] = a2; Bsh[bi][4*tid+3] = a3;
    if (tid == 63) Bsh[bi][256] = a4;
    Ksh[bi][tid] = K;
  }
  __syncthreads();
  if (!dir){
    const float impE = fminf(aL * f0, IMPCAP);
    const float al0 = a0 + impE;
    const float al1 = fmaf(impE, sk1f, a0) + a1;
    const float al2 = a2 + a1;
    const float al3 = fmaf(a1, s3f, a2) + a3;
    const float al4 = a4 + a3;
    const float alq[4] = {al0, al1, al2, al3};
    const float* Bb  = Bsh[bi];
    const int*   Kbp = Ksh[bi];
    const int twoL = 2 * L;
    float v = NEG2;
    #pragma unroll
    for (int q = 0; q < 4; ++q){
      const int s = 4*tid + q;
      const int u = twoL - s;
      if (u >= 0){
        int ul = u >> 2; if (ul > 63) ul = 63;
        const float av = alq[q], bv = Bb[u];
        if (av > 0.0f && bv > 0.0f)
          v = lae2_log2(v, log2_fast(av) + log2_fast(bv) + (float)(K + Kbp[ul]));
      }
    }
    if (tid == 63){
      const int u = twoL - 256;
      if (u >= 0 && al4 > 0.0f && Bb[u] > 0.0f)
        v = lae2_log2(v, log2_fast(al4) + log2_fast(Bb[u]) + (float)(K + Kbp[u >> 2]));
    }
    #pragma unroll
    for (int o = 1; o < 64; o <<= 1){
      const float u2 = __shfl_xor(v, o, 64);
      v = lae2_log2(v, u2);
    }
    if (tid == 0) costs[b] = -LN2F * v;
  }
}

extern "C" void kernel_launch(void* const* d_in, const int* in_sizes, int n_in,
                              void* d_out, int out_size, void* d_ws, size_t ws_size,
                              hipStream_t stream){
  const float* acts       = (const float*)d_in[0];
  const int*   labels     = (const int*)d_in[1];
  const int*   act_lens   = (const int*)d_in[2];
  const int*   label_lens = (const int*)d_in[3];
  float* out = (float*)d_out;

  const size_t aux_floats = 2 * (size_t)B_DIM * 260 + B_DIM;   // AL, BB, costs
  const size_t aux_ints   = 2 * (size_t)B_DIM * 64;            // KF, KB
  const size_t need2 = (2 * EMF + aux_floats + aux_ints + 64) * sizeof(float);
  const size_t need1 = (EMF + 64) * sizeof(float);

  if (ws_size >= need2){
    float* em_f  = (float*)d_ws;
    float* em_r  = em_f + EMF;
    float* AL    = em_r + EMF;
    float* BBp   = AL + (size_t)B_DIM * 260;
    int*   KF    = (int*)(BBp + (size_t)B_DIM * 260);
    int*   KB    = KF + (size_t)B_DIM * 64;
    float* costs = (float*)(KB + (size_t)B_DIM * 64);
    em2_kernel<<<(T_DIM * B_DIM) / 4, 256, 0, stream>>>(acts, labels, act_lens,
                                                        label_lens, em_f, em_r);
    ctcfb2_kernel<<<2 * B_DIM, 64, 0, stream>>>(em_f, em_r, labels, act_lens,
                                                label_lens, AL, KF, BBp, KB);
    comb_kernel<<<B_DIM, 64, 0, stream>>>(AL, KF, BBp, KB, label_lens, costs);
    sum_kernel<<<1, 64, 0, stream>>>(costs, out);
  } else {
    float* em    = (float*)d_ws;
    float* costs = em + EMF;
    em_kernel<<<(T_DIM * B_DIM) / 4, 256, 0, stream>>>(acts, labels, act_lens, label_lens, em);
    ctcfb_kernel<<<B_DIM / 4, 512, 0, stream>>>(em, labels, act_lens, label_lens, costs);
    sum_kernel<<<1, 64, 0, stream>>>(costs, out);
  }
}

// Round 10
// 106.164 us; speedup vs baseline: 2.4036x; 1.1000x over previous
//
#include <hip/hip_runtime.h>
#include <cstddef>

#define T_DIM 2048
#define B_DIM 64
#define V_DIM 128
#define LMAX  128
#define ROWF  132                      // (fallback path) floats per em row
#define EMF   ((size_t)B_DIM * T_DIM * ROWF)
#define INV_LN2 1.44269504088896340736f
#define LN2F    0.69314718055994530942f
#define NEG2   -1.0e30f
#define IMPCAP 1.0e20f

__device__ __forceinline__ float exp2_fast(float x){ return __builtin_amdgcn_exp2f(x); }
__device__ __forceinline__ float log2_fast(float x){ return __builtin_amdgcn_logf(x); }

__device__ __forceinline__ float lae2_log2(float a, float b){
  float m = fmaxf(a, b);
  float d = fabsf(a - b);
  return m + log2_fast(1.0f + exp2_fast(-d));
}

// DPP wave_shr:1 (validated R3-R9): lane n <- lane n-1.
__device__ __forceinline__ float dpp_shr1_bc(float src){   // lane 0 <- 0
  return __int_as_float(__builtin_amdgcn_update_dpp(
      0, __float_as_int(src), 0x138, 0xF, 0xF, true));
}
__device__ __forceinline__ int dpp_shr1_old_i(int oldv, int src){  // lane 0 keeps oldv
  return __builtin_amdgcn_update_dpp(oldv, src, 0x138, 0xF, 0xF, false);
}

// bf16 pack helpers (round-to-nearest-even-ish; inputs are finite probs)
__device__ __forceinline__ unsigned int f2bf(float x){
  unsigned int b = __float_as_uint(x);
  b += 0x7FFFu + ((b >> 16) & 1u);
  return b >> 16;
}
__device__ __forceinline__ unsigned int packbf2(float lo, float hi){
  return f2bf(lo) | (f2bf(hi) << 16);
}

// ---- shared step/boundary macros (R8/R9-proven algebra) --------------------
#define STEPF(p0v,p1v,pbv) { \
  const float t3_ = fmaf(a1, s3f, a2) + a3; \
  const float n3_ = (p1v) * t3_; \
  const float nL_ = dpp_shr1_bc(n3_); \
  const float imp_ = fminf(aL * f0, IMPCAP); \
  const float t1_ = fmaf(imp_, sk1f, a0) + a1; \
  const float n0_ = (pbv) * (a0 + imp_); \
  const float n1_ = (p0v) * t1_; \
  const float n2_ = (pbv) * (a2 + a1); \
  const float n4_ = (pbv) * (a4 + a3); \
  aL = nL_; a0=n0_; a1=n1_; a2=n2_; a3=n3_; a4=n4_; }

#define BOUNDF { \
  float m_ = fmaxf(fmaxf(fmaxf(a0,a1),fmaxf(a2,a3)),a4); \
  int e_; (void)frexpf(m_, &e_); \
  const float sc_ = ldexpf(1.0f, -e_); \
  a0*=sc_; a1*=sc_; a2*=sc_; a3*=sc_; a4*=sc_; \
  K += e_; \
  const int KL_ = dpp_shr1_old_i(K, K); \
  if (m_ == 0.0f) K = KL_; \
  int sh_ = KL_ - K; \
  if (tid > 0 && sh_ > 40){ \
    const int d_ = sh_ - 40; \
    const float dn_ = ldexpf(1.0f, -d_); \
    a0*=dn_; a1*=dn_; a2*=dn_; a3*=dn_; a4*=dn_; \
    K += d_; sh_ = 40; } \
  const float f_ = ldexpf(1.0f, sh_); \
  f0 = (tid == 0) ? 0.0f : f_; \
  aL = dpp_shr1_bc(a3); }

// ---- Kernel 1 (primary): softmax + bf16-packed dual emission streams -------
// PK[dir][b][i][lane] = u32 bf16x2 (p_lane0, p_lane1); dir=1 is label- AND
// time-reversed (i = alen-1-t) so both chain waves run identical fwd code.
// BK[dir][b][i] = bf16 blank prob (same time mapping).
__global__ __launch_bounds__(256) void em3_kernel(const float* __restrict__ acts,
                                                  const int* __restrict__ labels,
                                                  const int* __restrict__ act_lens,
                                                  const int* __restrict__ label_lens,
                                                  unsigned int* __restrict__ PK,
                                                  unsigned short* __restrict__ BK){
  const int wid  = threadIdx.x >> 6;
  const int lane = threadIdx.x & 63;
  const int row  = blockIdx.x * 4 + wid;          // row = t*B + b
  const int t = row >> 6;
  const int b = row & (B_DIM - 1);

  __shared__ float sh[4][V_DIM];

  const float2 v = ((const float2*)(acts + (size_t)row * V_DIM))[lane];
  float m = fmaxf(v.x, v.y);
  #pragma unroll
  for (int o = 32; o; o >>= 1) m = fmaxf(m, __shfl_xor(m, o, 64));
  float s = exp2_fast((v.x - m) * INV_LN2) + exp2_fast((v.y - m) * INV_LN2);
  #pragma unroll
  for (int o = 32; o; o >>= 1) s += __shfl_xor(s, o, 64);
  const float d2 = fmaf(m, INV_LN2, log2_fast(s));     // log2 softmax denom

  sh[wid][2 * lane]     = v.x;
  sh[wid][2 * lane + 1] = v.y;

  int masked = (lane < b) ? label_lens[lane] : 0;
  int off = masked;
  #pragma unroll
  for (int o = 1; o < 64; o <<= 1) off += __shfl_xor(off, o, 64);
  const int L = label_lens[b];

  __syncthreads();

  int alen = act_lens[b]; if (alen > T_DIM) alen = T_DIM; if (alen < 1) alen = 1;
  if (t >= alen) return;   // rows past act_len never read downstream

  const int j0 = 2 * lane, j1 = 2 * lane + 1;
  const int lab0 = (j0 < L) ? labels[off + j0] : 0;
  const int lab1 = (j1 < L) ? labels[off + j1] : 0;
  const int lr0  = (j0 < L) ? labels[off + (L - 1 - j0)] : 0;
  const int lr1  = (j1 < L) ? labels[off + (L - 1 - j1)] : 0;

  const float p0  = exp2_fast(fmaf(sh[wid][lab0], INV_LN2, -d2));
  const float p1  = exp2_fast(fmaf(sh[wid][lab1], INV_LN2, -d2));
  const float pr0 = exp2_fast(fmaf(sh[wid][lr0],  INV_LN2, -d2));
  const float pr1 = exp2_fast(fmaf(sh[wid][lr1],  INV_LN2, -d2));
  const float pb  = exp2_fast(fmaf(sh[wid][0],    INV_LN2, -d2));

  const int ir = alen - 1 - t;                     // time-reversed row index
  unsigned int* pf = PK + ((size_t)b * T_DIM + t) * 64;
  unsigned int* pr = PK + ((size_t)(B_DIM + b) * T_DIM + ir) * 64;
  pf[lane] = packbf2(p0, p1);
  pr[lane] = packbf2(pr0, pr1);
  if (lane == 0){
    BK[(size_t)b * T_DIM + t]             = (unsigned short)f2bf(pb);
    BK[(size_t)(B_DIM + b) * T_DIM + ir]  = (unsigned short)f2bf(pb);
  }
}

// ---- Kernel 2 (primary): one wave per (b,dir); identical fwd recursion -----
#define LOADG(BUF, BV, bi0) { _Pragma("unroll") \
  for (int k_ = 0; k_ < 8; ++k_){ \
    int i_ = (bi0) + k_; if (i_ > ns1) i_ = ns1; \
    BUF[k_] = pair_base[(size_t)i_ * 64]; } \
  int g_ = (bi0); if (g_ > ns1) g_ = ns1; \
  BV = *(const uint4*)(blank_base + (g_ & ~7)); }

#define STEPU(BUF, BV, kk) { \
  const unsigned int u_ = BUF[kk]; \
  const float p0v_ = __uint_as_float(u_ << 16); \
  const float p1v_ = __uint_as_float(u_ & 0xFFFF0000u); \
  const unsigned int bw_ = (((kk) >> 1) == 0 ? BV.x : ((kk) >> 1) == 1 ? BV.y \
                           : ((kk) >> 1) == 2 ? BV.z : BV.w); \
  const float pbv_ = __uint_as_float(((kk) & 1) ? (bw_ & 0xFFFF0000u) : (bw_ << 16)); \
  STEPF(p0v_, p1v_, pbv_) }

__global__ __launch_bounds__(64) void ctcfb3_kernel(const unsigned int* __restrict__ PK,
    const unsigned short* __restrict__ BK, const int* __restrict__ labels,
    const int* __restrict__ act_lens, const int* __restrict__ label_lens,
    float* __restrict__ AL, int* __restrict__ KF,
    float* __restrict__ BB, int* __restrict__ KB)
{
  const int tid = threadIdx.x;
  const int b   = blockIdx.x >> 1;
  const int dir = blockIdx.x & 1;

  const int L = label_lens[b];
  int alen = act_lens[b]; if (alen > T_DIM) alen = T_DIM; if (alen < 1) alen = 1;
  const int m = alen >> 1;

  int off = (tid < b) ? label_lens[tid] : 0;
  #pragma unroll
  for (int o = 1; o < 64; o <<= 1) off += __shfl_xor(off, o, 64);

  // skip flags from direction-dependent labels (emissions coherent by layout)
  const int j0 = 2*tid, j1 = 2*tid + 1, jm = 2*tid - 1;
  const int i0 = dir ? (L - 1 - j0) : j0;
  const int i1 = dir ? (L - 1 - j1) : j1;
  const int im = dir ? (L - 1 - jm) : jm;
  const int lab0  = (j0 < L) ? labels[off + i0] : 0;
  const int lab1  = (j1 < L) ? labels[off + i1] : 0;
  const int labm1 = (tid == 0) ? -1 : ((jm < L) ? labels[off + im] : 0);
  const float sk1f = ((lab0 != 0) && (lab0 != labm1)) ? 1.0f : 0.0f;
  const float s3f  = ((lab1 != 0) && (lab1 != lab0)) ? 1.0f : 0.0f;

  const int ns = dir ? (alen - m) : m;
  int ns1 = ns - 1; if (ns1 < 0) ns1 = 0;

  const unsigned int*   pair_base  = PK + ((size_t)(dir * B_DIM + b) * T_DIM) * 64 + tid;
  const unsigned short* blank_base = BK + (size_t)(dir * B_DIM + b) * T_DIM;

  float a0 = (tid == 0) ? 1.0f : 0.0f;
  float a1 = 0.f, a2 = 0.f, a3 = 0.f, a4 = 0.f;
  float aL = 0.f, f0 = 0.f;
  int K = 0;

  unsigned int PU[8], QU[8], RU[8];
  uint4 PB4, QB4, RB4;
  LOADG(PU, PB4, 0) LOADG(QU, QB4, 8) LOADG(RU, RB4, 16)   // 27 loads in flight

  int done = 0;
  for (; done + 24 <= ns; done += 24){
    BOUNDF
    #pragma unroll
    for (int k = 0; k < 8; ++k) STEPU(PU, PB4, k)
    LOADG(PU, PB4, done + 24)
    BOUNDF
    #pragma unroll
    for (int k = 0; k < 8; ++k) STEPU(QU, QB4, k)
    LOADG(QU, QB4, done + 32)
    BOUNDF
    #pragma unroll
    for (int k = 0; k < 8; ++k) STEPU(RU, RB4, k)
    LOADG(RU, RB4, done + 40)
  }
  const int r = ns - done;                 // 0..23
  if (r > 0){
    BOUNDF
    #pragma unroll
    for (int k = 0; k < 8; ++k){ if (k < r) STEPU(PU, PB4, k) }
  }
  if (r > 8){
    BOUNDF
    #pragma unroll
    for (int k = 0; k < 8; ++k){ if (8 + k < r) STEPU(QU, QB4, k) }
  }
  if (r > 16){
    BOUNDF
    #pragma unroll
    for (int k = 0; k < 8; ++k){ if (16 + k < r) STEPU(RU, RB4, k) }
  }

  if (dir){
    BB[b*260 + 4*tid]     = a0; BB[b*260 + 4*tid + 1] = a1;
    BB[b*260 + 4*tid + 2] = a2; BB[b*260 + 4*tid + 3] = a3;
    if (tid == 63) BB[b*260 + 256] = a4;
    KB[b*64 + tid] = K;
  } else {
    const float impE = fminf(aL * f0, IMPCAP);
    AL[b*260 + 4*tid]     = a0 + impE;
    AL[b*260 + 4*tid + 1] = fmaf(impE, sk1f, a0) + a1;
    AL[b*260 + 4*tid + 2] = a2 + a1;
    AL[b*260 + 4*tid + 3] = fmaf(a1, s3f, a2) + a3;
    if (tid == 63) AL[b*260 + 256] = a4 + a3;
    KF[b*64 + tid] = K;
  }
}

// ---- Kernel 3 (primary): per-b combine P = sum_s alphabar(s)*beta_m(s) ----
__global__ __launch_bounds__(64) void comb_kernel(const float* __restrict__ AL,
    const int* __restrict__ KF, const float* __restrict__ BB,
    const int* __restrict__ KB, const int* __restrict__ label_lens,
    float* __restrict__ costs)
{
  const int b = blockIdx.x, tid = threadIdx.x;
  const int twoL = 2 * label_lens[b];
  const int Kf = KF[b*64 + tid];

  float v = NEG2;
  #pragma unroll
  for (int q = 0; q < 4; ++q){
    const int s = 4*tid + q;
    const int u = twoL - s;
    if (u >= 0){
      int ul = u >> 2; if (ul > 63) ul = 63;
      const float av = AL[b*260 + s], bv = BB[b*260 + u];
      if (av > 0.0f && bv > 0.0f)
        v = lae2_log2(v, log2_fast(av) + log2_fast(bv)
                         + (float)(Kf + KB[b*64 + ul]));
    }
  }
  if (tid == 63){
    const int u = twoL - 256;               // only L=128 hits this
    const float av = AL[b*260 + 256];
    if (u >= 0 && av > 0.0f && BB[b*260 + u] > 0.0f)
      v = lae2_log2(v, log2_fast(av) + log2_fast(BB[b*260 + u])
                       + (float)(Kf + KB[b*64 + (u >> 2)]));
  }
  #pragma unroll
  for (int o = 1; o < 64; o <<= 1){
    const float u2 = __shfl_xor(v, o, 64);
    v = lae2_log2(v, u2);
  }
  if (tid == 0) costs[b] = -LN2F * v;
}

// ---- Kernel 4: deterministic sum ------------------------------------------
__global__ __launch_bounds__(64) void sum_kernel(const float* __restrict__ costs,
                                                 float* __restrict__ out){
  float v = costs[threadIdx.x];
  #pragma unroll
  for (int o = 32; o; o >>= 1) v += __shfl_xor(v, o, 64);
  if (threadIdx.x == 0) out[0] = v;
}

// ============== R8 PROVEN PATH (fallback when ws too small) ==================
__global__ __launch_bounds__(256) void em_kernel(const float* __restrict__ acts,
                                                 const int* __restrict__ labels,
                                                 const int* __restrict__ act_lens,
                                                 const int* __restrict__ label_lens,
                                                 float* __restrict__ em){
  const int wid  = threadIdx.x >> 6;
  const int lane = threadIdx.x & 63;
  const int row  = blockIdx.x * 4 + wid;
  const int t = row >> 6;
  const int b = row & (B_DIM - 1);
  __shared__ float sh[4][V_DIM];
  const float2 v = ((const float2*)(acts + (size_t)row * V_DIM))[lane];
  float m = fmaxf(v.x, v.y);
  #pragma unroll
  for (int o = 32; o; o >>= 1) m = fmaxf(m, __shfl_xor(m, o, 64));
  float s = exp2_fast((v.x - m) * INV_LN2) + exp2_fast((v.y - m) * INV_LN2);
  #pragma unroll
  for (int o = 32; o; o >>= 1) s += __shfl_xor(s, o, 64);
  const float d2 = fmaf(m, INV_LN2, log2_fast(s));
  sh[wid][2 * lane]     = v.x;
  sh[wid][2 * lane + 1] = v.y;
  int masked = (lane < b) ? label_lens[lane] : 0;
  int off = masked;
  #pragma unroll
  for (int o = 1; o < 64; o <<= 1) off += __shfl_xor(off, o, 64);
  const int L = label_lens[b];
  __syncthreads();
  if (t >= act_lens[b]) return;
  const int j0 = 2 * lane, j1 = 2 * lane + 1;
  const int lab0 = (j0 < L) ? labels[off + j0] : 0;
  const int lab1 = (j1 < L) ? labels[off + j1] : 0;
  const float p0 = exp2_fast(fmaf(sh[wid][lab0], INV_LN2, -d2));
  const float p1 = exp2_fast(fmaf(sh[wid][lab1], INV_LN2, -d2));
  float* er = em + ((size_t)b * T_DIM + t) * ROWF;
  ((float2*)er)[lane] = make_float2(p0, p1);
  if (lane == 0) er[128] = exp2_fast(fmaf(sh[wid][0], INV_LN2, -d2));
}

#define LOADD(BUF, BBUF, bi0) { _Pragma("unroll") \
  for (int k_ = 0; k_ < 8; ++k_){ \
    int i_ = (bi0) + k_; if (i_ > ns1) i_ = ns1; \
    const float* r_ = em_b + (size_t)(rbase + rsgn * i_) * ROWF; \
    BUF[k_].x = r_[ex0]; BUF[k_].y = r_[ex1]; BBUF[k_] = r_[128]; } }

__global__ __launch_bounds__(512) void ctcfb_kernel(const float* __restrict__ em,
    const int* __restrict__ labels, const int* __restrict__ act_lens,
    const int* __restrict__ label_lens, float* __restrict__ costs)
{
  __shared__ float Bsh[4][260];
  __shared__ int   Ksh[4][64];
  const int tid = threadIdx.x & 63;
  const int w   = threadIdx.x >> 6;
  const int bi  = w >> 1;
  const int dir = w & 1;
  const int b   = blockIdx.x * 4 + bi;
  const int L = label_lens[b];
  int alen = act_lens[b]; if (alen > T_DIM) alen = T_DIM; if (alen < 1) alen = 1;
  const int m = alen >> 1;
  int off = (tid < b) ? label_lens[tid] : 0;
  #pragma unroll
  for (int o = 1; o < 64; o <<= 1) off += __shfl_xor(off, o, 64);
  const int j0 = 2*tid, j1 = 2*tid + 1, jm = 2*tid - 1;
  const int i0 = dir ? (L - 1 - j0) : j0;
  const int i1 = dir ? (L - 1 - j1) : j1;
  const int im = dir ? (L - 1 - jm) : jm;
  const int lab0  = (j0 < L) ? labels[off + i0] : 0;
  const int lab1  = (j1 < L) ? labels[off + i1] : 0;
  const int labm1 = (tid == 0) ? -1 : ((jm < L) ? labels[off + im] : 0);
  const float sk1f = ((lab0 != 0) && (lab0 != labm1)) ? 1.0f : 0.0f;
  const float s3f = ((lab1 != 0) && (lab1 != lab0)) ? 1.0f : 0.0f;
  const int ex0 = (i0 < 0) ? 0 : i0;
  const int ex1 = (i1 < 0) ? 0 : i1;
  const int ns  = dir ? (alen - m) : m;
  int ns1 = ns - 1; if (ns1 < 0) ns1 = 0;
  const int rbase = dir ? (alen - 1) : 0;
  const int rsgn  = dir ? -1 : 1;
  const float* em_b = em + (size_t)b * T_DIM * ROWF;
  float a0 = (tid == 0) ? 1.0f : 0.0f;
  float a1 = 0.f, a2 = 0.f, a3 = 0.f, a4 = 0.f;
  float aL = 0.f, f0 = 0.f;
  int K = 0;
  float2 P[8], Q[8]; float Pb[8], Qb[8];
  if (ns > 0){ LOADD(P, Pb, 0) }
  int done = 0;
  for (; done + 16 <= ns; done += 16){
    LOADD(Q, Qb, done + 8)
    BOUNDF
    #pragma unroll
    for (int k = 0; k < 8; ++k) STEPF(P[k].x, P[k].y, Pb[k])
    LOADD(P, Pb, done + 16)
    BOUNDF
    #pragma unroll
    for (int k = 0; k < 8; ++k) STEPF(Q[k].x, Q[k].y, Qb[k])
  }
  const int remv = ns - done;
  if (remv >= 8){
    LOADD(Q, Qb, done + 8)
    BOUNDF
    #pragma unroll
    for (int k = 0; k < 8; ++k) STEPF(P[k].x, P[k].y, Pb[k])
    const int r2 = remv - 8;
    if (r2 > 0){
      BOUNDF
      #pragma unroll
      for (int k = 0; k < 8; ++k){ if (k < r2) STEPF(Q[k].x, Q[k].y, Qb[k]) }
    }
  } else if (remv > 0){
    BOUNDF
    #pragma unroll
    for (int k = 0; k < 8; ++k){ if (k < remv) STEPF(P[k].x, P[k].y, Pb[k]) }
  }
  if (dir){
    Bsh[bi][4*tid]   = a0; Bsh[bi][4*tid+1] = a1;
    Bsh[bi][4*tid+2] = a2; Bsh[bi][4*tid+3] = a3;
    if (tid == 63) Bsh[bi][256] = a4;
    Ksh[bi][tid] = K;
  }
  __syncthreads();
  if (!dir){
    const float impE = fminf(aL * f0, IMPCAP);
    const float al0 = a0 + impE;
    const float al1 = fmaf(impE, sk1f, a0) + a1;
    const float al2 = a2 + a1;
    const float al3 = fmaf(a1, s3f, a2) + a3;
    const float al4 = a4 + a3;
    const float alq[4] = {al0, al1, al2, al3};
    const float* Bb  = Bsh[bi];
    const int*   Kbp = Ksh[bi];
    const int twoL = 2 * L;
    float v = NEG2;
    #pragma unroll
    for (int q = 0; q < 4; ++q){
      const int s = 4*tid + q;
      const int u = twoL - s;
      if (u >= 0){
        int ul = u >> 2; if (ul > 63) ul = 63;
        const float av = alq[q], bv = Bb[u];
        if (av > 0.0f && bv > 0.0f)
          v = lae2_log2(v, log2_fast(av) + log2_fast(bv) + (float)(K + Kbp[ul]));
      }
    }
    if (tid == 63){
      const int u = twoL - 256;
      if (u >= 0 && al4 > 0.0f && Bb[u] > 0.0f)
        v = lae2_log2(v, log2_fast(al4) + log2_fast(Bb[u]) + (float)(K + Kbp[u >> 2]));
    }
    #pragma unroll
    for (int o = 1; o < 64; o <<= 1){
      const float u2 = __shfl_xor(v, o, 64);
      v = lae2_log2(v, u2);
    }
    if (tid == 0) costs[b] = -LN2F * v;
  }
}

extern "C" void kernel_launch(void* const* d_in, const int* in_sizes, int n_in,
                              void* d_out, int out_size, void* d_ws, size_t ws_size,
                              hipStream_t stream){
  const float* acts       = (const float*)d_in[0];
  const int*   labels     = (const int*)d_in[1];
  const int*   act_lens   = (const int*)d_in[2];
  const int*   label_lens = (const int*)d_in[3];
  float* out = (float*)d_out;

  const size_t pk_u32  = 2ull * B_DIM * T_DIM * 64;      // 16.78M u32 = 64 MB
  const size_t bk_u16  = 2ull * B_DIM * T_DIM;           // 512 KB
  const size_t need3 = pk_u32*4 + bk_u16*2
                     + (2ull*B_DIM*260 + B_DIM)*4 + (2ull*B_DIM*64)*4 + 256;
  const size_t need1 = (EMF + 64) * sizeof(float);

  if (ws_size >= need3){
    unsigned int*   PK = (unsigned int*)d_ws;
    unsigned short* BK = (unsigned short*)(PK + pk_u32);
    float* AL    = (float*)(BK + bk_u16);
    float* BBp   = AL + (size_t)B_DIM * 260;
    int*   KF    = (int*)(BBp + (size_t)B_DIM * 260);
    int*   KB    = KF + (size_t)B_DIM * 64;
    float* costs = (float*)(KB + (size_t)B_DIM * 64);
    em3_kernel<<<(T_DIM * B_DIM) / 4, 256, 0, stream>>>(acts, labels, act_lens,
                                                        label_lens, PK, BK);
    ctcfb3_kernel<<<2 * B_DIM, 64, 0, stream>>>(PK, BK, labels, act_lens,
                                                label_lens, AL, KF, BBp, KB);
    comb_kernel<<<B_DIM, 64, 0, stream>>>(AL, KF, BBp, KB, label_lens, costs);
    sum_kernel<<<1, 64, 0, stream>>>(costs, out);
  } else {
    float* em    = (float*)d_ws;
    float* costs = em + EMF;
    em_kernel<<<(T_DIM * B_DIM) / 4, 256, 0, stream>>>(acts, labels, act_lens, label_lens, em);
    ctcfb_kernel<<<B_DIM / 4, 512, 0, stream>>>(em, labels, act_lens, label_lens, costs);
    sum_kernel<<<1, 64, 0, stream>>>(costs, out);
  }
}